// Round 1
// baseline (1387.554 us; speedup 1.0000x reference)
//
#include <hip/hip_runtime.h>

#define B_ 256
#define D_ 128
#define T_ 1024
#define H_ 64
#define G_ 192   // 3H

__device__ __forceinline__ float sigmoidf_(float x) {
    return 1.0f / (1.0f + __expf(-x));
}
__device__ __forceinline__ float tanhf_(float x) {
    x = fminf(fmaxf(x, -15.0f), 15.0f);
    float e = __expf(2.0f * x);
    return (e - 1.0f) / (e + 1.0f);
}

// LDS-only barrier: does NOT drain vmcnt, so global prefetch loads stay in
// flight across steps (unlike __syncthreads, which drains vmcnt before
// s_barrier and would expose HBM latency every step).
__device__ __forceinline__ void bar_lds() {
    __builtin_amdgcn_sched_barrier(0);
    asm volatile("s_waitcnt lgkmcnt(0)" ::: "memory");
    __builtin_amdgcn_s_barrier();
    __builtin_amdgcn_sched_barrier(0);
}

// xg[b][t_local][g] = b_ih[g] + sum_d lat[b][d][t0+t_local] * W_ih[g][d]
__global__ __launch_bounds__(256) void gru_gemm(
    const float* __restrict__ lat, const float* __restrict__ W_ih,
    const float* __restrict__ b_ih, float* __restrict__ xg, int t0base)
{
    const int b    = blockIdx.x;
    const int tile = blockIdx.y;
    const int t0   = t0base + tile * 64;
    const int tl0  = tile * 64;
    const int tt   = threadIdx.x & 63;
    const int gg   = threadIdx.x >> 6;   // wave id, uniform

    const float* latb = lat + (size_t)b * (D_ * T_) + t0 + tt;

    float acc[48];
#pragma unroll
    for (int j = 0; j < 48; j++) acc[j] = b_ih[gg * 48 + j];  // uniform -> s_load

    for (int d0 = 0; d0 < D_; d0 += 8) {
        float lv[8];
#pragma unroll
        for (int dd = 0; dd < 8; dd++) lv[dd] = latb[(size_t)(d0 + dd) * T_];
#pragma unroll
        for (int j = 0; j < 48; j++) {
            const float* wr = W_ih + (gg * 48 + j) * D_ + d0;  // uniform -> s_load
#pragma unroll
            for (int dd = 0; dd < 8; dd++) acc[j] = fmaf(lv[dd], wr[dd], acc[j]);
        }
    }

    // stage to LDS (pad 193 -> conflict-free), then coalesced global write
    __shared__ float ts[64 * 193];
#pragma unroll
    for (int j = 0; j < 48; j++) ts[tt * 193 + gg * 48 + j] = acc[j];
    __syncthreads();

    float* outb = xg + ((size_t)b * (gridDim.y * 64) + tl0) * G_;
#pragma unroll
    for (int i = 0; i < 48; i++) {
        int flat = (int)threadIdx.x + 256 * i;
        int row  = flat / G_;
        int col  = flat - row * G_;
        outb[(size_t)row * G_ + col] = ts[row * 193 + col];
    }
}

// One block per batch row; 192 threads = one per gate pre-activation.
__global__ __launch_bounds__(192) void gru_scan(
    const float* __restrict__ xg, float* __restrict__ h_ws,
    const float* __restrict__ W_hh, const float* __restrict__ b_hh,
    const float* __restrict__ hidden_init,
    const float* __restrict__ head_w, const float* __restrict__ head_b,
    float* __restrict__ out, int TC, int first, int last)
{
    const int b = blockIdx.x;
    const int g = threadIdx.x;

    __shared__ float h_lds[H_];
    __shared__ float pre_rz[2 * H_];
    __shared__ float xn_lds[H_];
    __shared__ float hn_lds[H_];

    // W_hh row for this gate in VGPRs (16 float4 = 64 regs)
    float4 w4[16];
    {
        const float4* wr = (const float4*)(W_hh + g * H_);
#pragma unroll
        for (int i = 0; i < 16; i++) w4[i] = wr[i];
    }
    const float bh = b_hh[g];

    if (g < H_) h_lds[g] = first ? hidden_init[b * H_ + g] : h_ws[b * H_ + g];
    __syncthreads();

    const float* xgb = xg + (size_t)b * TC * G_ + g;

    // depth-4 prefetch ring (static indices; loop unrolled by 4)
    float x0 = xgb[0 * G_], x1 = xgb[1 * G_], x2 = xgb[2 * G_], x3 = xgb[3 * G_];

#define STEP(XC, TIDX) do {                                                  \
        float xnew_ = xgb[(size_t)((TIDX) + 4) * G_];                        \
        float a0 = 0.f, a1 = 0.f, a2 = 0.f, a3 = 0.f;                        \
        const float4* h4_ = (const float4*)h_lds;                            \
        _Pragma("unroll")                                                    \
        for (int k = 0; k < 16; k++) {                                       \
            float4 hv = h4_[k];  /* broadcast ds_read_b128 */                \
            a0 = fmaf(w4[k].x, hv.x, a0); a1 = fmaf(w4[k].y, hv.y, a1);      \
            a2 = fmaf(w4[k].z, hv.z, a2); a3 = fmaf(w4[k].w, hv.w, a3);      \
        }                                                                    \
        float hg_ = (a0 + a1) + (a2 + a3) + bh;                              \
        if (g < 2 * H_) pre_rz[g] = (XC) + hg_;                              \
        else { xn_lds[g - 2 * H_] = (XC); hn_lds[g - 2 * H_] = hg_; }        \
        bar_lds();                                                           \
        if (g < H_) {                                                        \
            float r_ = sigmoidf_(pre_rz[g]);                                 \
            float z_ = sigmoidf_(pre_rz[H_ + g]);                            \
            float n_ = tanhf_(xn_lds[g] + r_ * hn_lds[g]);                   \
            h_lds[g] = (1.0f - z_) * n_ + z_ * h_lds[g];                     \
        }                                                                    \
        bar_lds();                                                           \
        (XC) = xnew_;                                                        \
    } while (0)

    for (int t = 0; t < TC; t += 4) {
        STEP(x0, t);
        STEP(x1, t + 1);
        STEP(x2, t + 2);
        STEP(x3, t + 3);
    }
#undef STEP

    if (last) {
        if (g < H_) {
            float hj = h_lds[g];
            out[B_ + b * H_ + g] = hj;          // output 1: final hidden [1,B,H]
            float v = hj * head_w[g];
#pragma unroll
            for (int off = 32; off > 0; off >>= 1) v += __shfl_down(v, off);
            if (g == 0) out[b] = v + head_b[0]; // output 0: log_scale [B,1]
        }
    } else {
        if (g < H_) h_ws[b * H_ + g] = h_lds[g];
    }
}

extern "C" void kernel_launch(void* const* d_in, const int* in_sizes, int n_in,
                              void* d_out, int out_size, void* d_ws, size_t ws_size,
                              hipStream_t stream)
{
    const float* lat   = (const float*)d_in[0];
    const float* hid0  = (const float*)d_in[1];
    const float* W_ih  = (const float*)d_in[2];
    const float* W_hh  = (const float*)d_in[3];
    const float* b_ih  = (const float*)d_in[4];
    const float* b_hh  = (const float*)d_in[5];
    const float* headw = (const float*)d_in[6];
    const float* headb = (const float*)d_in[7];
    float* out = (float*)d_out;

    // pick largest chunk TC (multiple of 64) whose xg buffer fits in ws
    int TC = 256;
    auto need = [](int tc) {
        return (size_t)B_ * tc * G_ * 4 + 4 * G_ * 4 /*prefetch pad*/ +
               4096 + (size_t)B_ * H_ * 4;
    };
    while (TC > 64 && need(TC) > ws_size) TC >>= 1;

    size_t xg_bytes = ((size_t)B_ * TC * G_ * 4 + 4 * G_ * 4 + 255) / 256 * 256;
    float* xg   = (float*)d_ws;
    float* h_ws = (float*)((char*)d_ws + xg_bytes);

    const int nchunks = T_ / TC;
    for (int c = 0; c < nchunks; ++c) {
        dim3 ggrid(B_, TC / 64);
        gru_gemm<<<ggrid, dim3(256), 0, stream>>>(lat, W_ih, b_ih, xg, c * TC);
        gru_scan<<<dim3(B_), dim3(192), 0, stream>>>(
            xg, h_ws, W_hh, b_hh, hid0, headw, headb, out,
            TC, c == 0 ? 1 : 0, c == nchunks - 1 ? 1 : 0);
    }
}

// Round 2
// 1026.182 us; speedup vs baseline: 1.3522x; 1.3522x over previous
//
#include <hip/hip_runtime.h>

#define B_ 256
#define D_ 128
#define T_ 1024
#define H_ 64
#define G_ 192   // 3H
#define KC 32    // k-chunk staged in LDS

__device__ __forceinline__ float sigmoidf_(float x) {
    return 1.0f / (1.0f + __expf(-x));
}
__device__ __forceinline__ float tanhf_(float x) {
    x = fminf(fmaxf(x, -15.0f), 15.0f);
    float e = __expf(2.0f * x);
    return (e - 1.0f) / (e + 1.0f);
}

// LDS-only barrier: does NOT drain vmcnt, so global prefetch loads stay in
// flight across steps (unlike __syncthreads, which drains vmcnt).
__device__ __forceinline__ void bar_lds() {
    __builtin_amdgcn_sched_barrier(0);
    asm volatile("s_waitcnt lgkmcnt(0)" ::: "memory");
    __builtin_amdgcn_s_barrier();
    __builtin_amdgcn_sched_barrier(0);
}

// Register-tiled GEMM: xg[b][t][g] = b_ih[g] + sum_d lat[b][d][t]*W_ih[g][d]
// Block: one (b, 64-t tile). 256 threads, thread tile 8t x 6g.
// LDS: lat tile [128][64] + W chunk [KC][193] (padded -> conflict-free).
__global__ __launch_bounds__(256) void gru_gemm(
    const float* __restrict__ lat, const float* __restrict__ W_ih,
    const float* __restrict__ b_ih, float* __restrict__ xg, int t0base)
{
    __shared__ float smem[128 * 64 + KC * 193];  // 14368 floats = 57.5 KB
    float* lat_s = smem;             // [d][t] 128x64
    float* w_s   = smem + 128 * 64;  // [kk][g] KCx193

    const int b    = blockIdx.x;
    const int tile = blockIdx.y;
    const int t0   = t0base + tile * 64;
    const int tid  = threadIdx.x;
    const int tx   = tid & 7;    // t-group: t = tx*8 .. tx*8+7
    const int ty   = tid >> 3;   // g-group: g = ty*6 .. ty*6+5 (0..31)

    // stage lat tile [d][t] — coalesced global reads, conflict-free LDS writes
    {
        const float* src = lat + (size_t)b * (D_ * T_) + t0;
#pragma unroll
        for (int i = 0; i < 32; i++) {
            int f = tid + 256 * i;          // f = d*64 + t
            int d = f >> 6, t = f & 63;
            lat_s[f] = src[(size_t)d * T_ + t];
        }
    }

    float acc[8][6];
#pragma unroll
    for (int j = 0; j < 8; j++)
#pragma unroll
        for (int i = 0; i < 6; i++) acc[j][i] = 0.0f;

    for (int kc = 0; kc < D_; kc += KC) {
        __syncthreads();
        // stage W chunk transposed: w_s[kk][g] = W_ih[g][kc+kk]
#pragma unroll
        for (int i = 0; i < (G_ * KC) / 256; i++) {   // 24 per thread
            int f = tid + 256 * i;
            int g = f >> 5, kk = f & 31;
            w_s[kk * 193 + g] = W_ih[g * D_ + kc + kk];
        }
        __syncthreads();
#pragma unroll 8
        for (int k = 0; k < KC; k++) {
            float4 l0 = *(const float4*)&lat_s[(kc + k) * 64 + tx * 8];
            float4 l1 = *(const float4*)&lat_s[(kc + k) * 64 + tx * 8 + 4];
            float2 w0 = *(const float2*)&w_s[k * 193 + ty * 6];
            float2 w1 = *(const float2*)&w_s[k * 193 + ty * 6 + 2];
            float2 w2 = *(const float2*)&w_s[k * 193 + ty * 6 + 4];
            float lv[8] = {l0.x, l0.y, l0.z, l0.w, l1.x, l1.y, l1.z, l1.w};
            float wv[6] = {w0.x, w0.y, w1.x, w1.y, w2.x, w2.y};
#pragma unroll
            for (int j = 0; j < 8; j++)
#pragma unroll
                for (int i = 0; i < 6; i++)
                    acc[j][i] = fmaf(lv[j], wv[i], acc[j][i]);
        }
    }
    __syncthreads();

    // bias
    float bias[6];
#pragma unroll
    for (int i = 0; i < 6; i++) bias[i] = b_ih[ty * 6 + i];

    // epilogue: LDS transpose (reuse smem; 64*193 = 12352 <= 14368), then
    // coalesced global store
    float* ts = smem;
#pragma unroll
    for (int j = 0; j < 8; j++)
#pragma unroll
        for (int i = 0; i < 6; i++)
            ts[(tx * 8 + j) * 193 + ty * 6 + i] = acc[j][i] + bias[i];
    __syncthreads();

    float* outb = xg + ((size_t)b * (gridDim.y * 64) + tile * 64) * G_;
#pragma unroll
    for (int i = 0; i < 48; i++) {
        int f = tid + 256 * i;          // < 12288
        int row = f / G_;
        int col = f - row * G_;
        outb[(size_t)row * G_ + col] = ts[row * 193 + col];
    }
}

// One block per batch row; 192 threads = one per gate pre-activation.
__global__ __launch_bounds__(192) void gru_scan(
    const float* __restrict__ xg, float* __restrict__ h_ws,
    const float* __restrict__ W_hh, const float* __restrict__ b_hh,
    const float* __restrict__ hidden_init,
    const float* __restrict__ head_w, const float* __restrict__ head_b,
    float* __restrict__ out, int TC, int first, int last)
{
    const int b = blockIdx.x;
    const int g = threadIdx.x;

    __shared__ float h_lds[H_];
    __shared__ float pre_rz[2 * H_];
    __shared__ float xn_lds[H_];
    __shared__ float hn_lds[H_];

    // W_hh row for this gate in VGPRs (16 float4 = 64 regs)
    float4 w4[16];
    {
        const float4* wr = (const float4*)(W_hh + g * H_);
#pragma unroll
        for (int i = 0; i < 16; i++) w4[i] = wr[i];
    }
    const float bh = b_hh[g];

    if (g < H_) h_lds[g] = first ? hidden_init[b * H_ + g] : h_ws[b * H_ + g];
    __syncthreads();

    const float* xgb = xg + (size_t)b * TC * G_ + g;

    // depth-4 prefetch ring (static indices; loop unrolled by 4)
    float x0 = xgb[0 * G_], x1 = xgb[1 * G_], x2 = xgb[2 * G_], x3 = xgb[3 * G_];

#define STEP(XC, TIDX) do {                                                  \
        float xnew_ = xgb[(size_t)((TIDX) + 4) * G_];                        \
        float a0 = 0.f, a1 = 0.f, a2 = 0.f, a3 = 0.f;                        \
        const float4* h4_ = (const float4*)h_lds;                            \
        _Pragma("unroll")                                                    \
        for (int k = 0; k < 16; k++) {                                       \
            float4 hv = h4_[k];  /* broadcast ds_read_b128 */                \
            a0 = fmaf(w4[k].x, hv.x, a0); a1 = fmaf(w4[k].y, hv.y, a1);      \
            a2 = fmaf(w4[k].z, hv.z, a2); a3 = fmaf(w4[k].w, hv.w, a3);      \
        }                                                                    \
        float hg_ = (a0 + a1) + (a2 + a3) + bh;                              \
        if (g < 2 * H_) pre_rz[g] = (XC) + hg_;                              \
        else { xn_lds[g - 2 * H_] = (XC); hn_lds[g - 2 * H_] = hg_; }        \
        bar_lds();                                                           \
        if (g < H_) {                                                        \
            float r_ = sigmoidf_(pre_rz[g]);                                 \
            float z_ = sigmoidf_(pre_rz[H_ + g]);                            \
            float n_ = tanhf_(xn_lds[g] + r_ * hn_lds[g]);                   \
            h_lds[g] = (1.0f - z_) * n_ + z_ * h_lds[g];                     \
        }                                                                    \
        bar_lds();                                                           \
        (XC) = xnew_;                                                        \
    } while (0)

    for (int t = 0; t < TC; t += 4) {
        STEP(x0, t);
        STEP(x1, t + 1);
        STEP(x2, t + 2);
        STEP(x3, t + 3);
    }
#undef STEP

    if (last) {
        if (g < H_) {
            float hj = h_lds[g];
            out[B_ + b * H_ + g] = hj;          // output 1: final hidden [1,B,H]
            float v = hj * head_w[g];
#pragma unroll
            for (int off = 32; off > 0; off >>= 1) v += __shfl_down(v, off);
            if (g == 0) out[b] = v + head_b[0]; // output 0: log_scale [B,1]
        }
    } else {
        if (g < H_) h_ws[b * H_ + g] = h_lds[g];
    }
}

extern "C" void kernel_launch(void* const* d_in, const int* in_sizes, int n_in,
                              void* d_out, int out_size, void* d_ws, size_t ws_size,
                              hipStream_t stream)
{
    const float* lat   = (const float*)d_in[0];
    const float* hid0  = (const float*)d_in[1];
    const float* W_ih  = (const float*)d_in[2];
    const float* W_hh  = (const float*)d_in[3];
    const float* b_ih  = (const float*)d_in[4];
    const float* b_hh  = (const float*)d_in[5];
    const float* headw = (const float*)d_in[6];
    const float* headb = (const float*)d_in[7];
    float* out = (float*)d_out;

    // pick largest chunk TC (multiple of 64) whose xg buffer fits in ws
    int TC = 256;
    auto need = [](int tc) {
        return (size_t)B_ * tc * G_ * 4 + 4 * G_ * 4 /*prefetch pad*/ +
               4096 + (size_t)B_ * H_ * 4;
    };
    while (TC > 64 && need(TC) > ws_size) TC >>= 1;

    size_t xg_bytes = ((size_t)B_ * TC * G_ * 4 + 4 * G_ * 4 + 255) / 256 * 256;
    float* xg   = (float*)d_ws;
    float* h_ws = (float*)((char*)d_ws + xg_bytes);

    const int nchunks = T_ / TC;
    for (int c = 0; c < nchunks; ++c) {
        dim3 ggrid(B_, TC / 64);
        gru_gemm<<<ggrid, dim3(256), 0, stream>>>(lat, W_ih, b_ih, xg, c * TC);
        gru_scan<<<dim3(B_), dim3(192), 0, stream>>>(
            xg, h_ws, W_hh, b_hh, hid0, headw, headb, out,
            TC, c == 0 ? 1 : 0, c == nchunks - 1 ? 1 : 0);
    }
}